// Round 6
// baseline (47.540 us; speedup 1.0000x reference)
//
#include <hip/hip_runtime.h>
#include <math.h>

#define EPSF 1e-7f
#define NT 1024   // K2: 16 waves/block
#define NTF 256   // final kernel

// anchors / stride, exact binary fractions
__device__ __constant__ float d_anch[3][3][2] = {
    {{10.f/8.f,  13.f/8.f},  {16.f/8.f,  30.f/8.f},  {33.f/8.f,  23.f/8.f}},
    {{30.f/16.f, 61.f/16.f}, {62.f/16.f, 45.f/16.f}, {59.f/16.f, 119.f/16.f}},
    {{116.f/32.f,90.f/32.f}, {156.f/32.f,198.f/32.f},{373.f/32.f,326.f/32.f}},
};

__device__ __forceinline__ float bce0(float x) {           // bce(x, 0)
    return fmaxf(x, 0.0f) + log1pf(expf(-fabsf(x)));
}
__device__ __forceinline__ float bcef(float x, float t) {  // full bce
    return fmaxf(x, 0.0f) - x * t + log1pf(expf(-fabsf(x)));
}
__device__ __forceinline__ float sigm(float x) {
    return 1.0f / (1.0f + expf(-x));
}

template <int NTH>
__device__ __forceinline__ float block_reduce(float v, float* s) {
    s[threadIdx.x] = v;
    __syncthreads();
    for (int st = NTH / 2; st > 0; st >>= 1) {
        if (threadIdx.x < st) s[threadIdx.x] += s[threadIdx.x + st];
        __syncthreads();
    }
    float r = s[0];
    __syncthreads();
    return r;
}

// ---------------------------------------------------------------------------
// K1: zero tobj ONLY (orders the zero before K2's atomics via kernel boundary)
// ---------------------------------------------------------------------------
__global__ void zero_kernel(float4* __restrict__ p, int n4)
{
    int i = blockIdx.x * NT + threadIdx.x;
    if (i < n4) p[i] = make_float4(0.f, 0.f, 0.f, 0.f);
}

// ---------------------------------------------------------------------------
// K2: fused. Blocks [0, sweepBlocks) stream the obj bce(x,0) term over all
// cells; blocks [sweepBlocks, ...) do per-entry work (wave per entry):
// CIoU -> lbox/cnt, coalesced 80-class BCE, telescoping-max corr term
//   (sum over entries of w*x*(new-old) == sum_cells w*x*tobj_final).
// Per-block partials {lbox, cnt, cls, corr, obj}.
// ---------------------------------------------------------------------------
__global__ void fused_kernel(const float* __restrict__ pred0,
                             const float* __restrict__ pred1,
                             const float* __restrict__ pred2,
                             const float* __restrict__ targets,
                             int nt, int sweepBlocks, int bpl2,
                             float* __restrict__ tobj_base,
                             float* __restrict__ blockpart,  // [grid][5]
                             int n0, int n1, int n2)
{
    float lbox = 0.0f, cnt = 0.0f, corr = 0.0f, clsacc = 0.0f, objacc = 0.0f;

    if (blockIdx.x < sweepBlocks) {
        // ---- sweep role: obj BCE(x,0) term ----
        int idx = blockIdx.x * NT + threadIdx.x;
        int N = n0 + n1 + n2;
        if (idx < N) {
            const float* pred; int cell; float w;
            if (idx < n0)           { pred = pred0; cell = idx;           w = 4.0f / (float)n0; }
            else if (idx < n0 + n1) { pred = pred1; cell = idx - n0;      w = 1.0f / (float)n1; }
            else                    { pred = pred2; cell = idx - n0 - n1; w = 0.4f / (float)n2; }
            objacc = w * bce0(pred[(size_t)cell * 85 + 4]);
        }
    } else {
        // ---- entry role ----
        int eb    = blockIdx.x - sweepBlocks;
        int layer = eb / bpl2;
        int sub   = eb % bpl2;
        int wid   = threadIdx.x >> 6;
        int lane  = threadIdx.x & 63;
        int perLayer = 15 * nt;
        int eL = sub * 16 + wid;

        const float* pred; float* tobj; int H, W; float wl;
        if (layer == 0)      { pred = pred0; tobj = tobj_base;           H = 80; W = 80; wl = 4.0f / (float)n0; }
        else if (layer == 1) { pred = pred1; tobj = tobj_base + n0;      H = 40; W = 40; wl = 1.0f / (float)n1; }
        else                 { pred = pred2; tobj = tobj_base + n0 + n1; H = 20; W = 20; wl = 0.4f / (float)n2; }

        if (eL < perLayer) {
            int t = eL % nt;
            int a = (eL / nt) % 3;
            int o = eL / (nt * 3);

            const float* tg = targets + t * 6;
            float tb = tg[0], tc = tg[1];
            float gx = tg[2] * (float)W, gy = tg[3] * (float)H;
            float gw = tg[4] * (float)W, gh = tg[5] * (float)H;

            float aw = d_anch[layer][a][0], ah = d_anch[layer][a][1];
            float rw = gw / (aw + 1e-16f), rh = gh / (ah + 1e-16f);
            float rmax = fmaxf(fmaxf(rw, 1.0f / rw), fmaxf(rh, 1.0f / rh));
            bool aok = rmax < 4.0f;

            float fxi = floorf(gx), fyi = floorf(gy);
            float fx = gx - fxi, fy = gy - fyi;
            bool selo;
            switch (o) {
                case 0: selo = true; break;
                case 1: selo = (fx > 0.5f) && (fxi < (float)(W - 1)); break;
                case 2: selo = (fy > 0.5f) && (fyi < (float)(H - 1)); break;
                case 3: selo = (fx < 0.5f) && (fxi > 0.0f); break;
                default: selo = (fy < 0.5f) && (fyi > 0.0f); break;
            }

            if (aok && selo) {
                float ox = (o == 1) ? 1.0f : (o == 3) ? -1.0f : 0.0f;
                float oy = (o == 2) ? 1.0f : (o == 4) ? -1.0f : 0.0f;
                float gex = gx - ox, gey = gy - oy;
                int gix = min(max((int)floorf(gex), 0), W - 1);
                int giy = min(max((int)floorf(gey), 0), H - 1);
                float txc = gex - (float)gix, tyc = gey - (float)giy;
                float tx1 = txc - gw * 0.5f, ty1 = tyc - gh * 0.5f;
                float tx2 = txc + gw * 0.5f, ty2 = tyc + gh * 0.5f;

                int b = (int)tb, cls = (int)tc;
                int cell = (int)(((((size_t)b * 3 + a) * H + giy) * W + gix));
                const float* pm = pred + (size_t)cell * 85;

                // scalar part redundantly on all lanes (broadcast loads)
                float p0 = pm[0], p1v = pm[1], p2v = pm[2], p3 = pm[3];
                float pxc = sigm(p0) * 2.0f - 0.5f;
                float pyc = sigm(p1v) * 2.0f - 0.5f;
                float sw = sigm(p2v) * 2.0f;
                float sh = sigm(p3) * 2.0f;
                float pw = sw * sw * aw, ph = sh * sh * ah;
                float px1 = pxc - pw * 0.5f, py1 = pyc - ph * 0.5f;
                float px2 = pxc + pw * 0.5f, py2 = pyc + ph * 0.5f;

                float ix1 = fmaxf(px1, tx1), iy1 = fmaxf(py1, ty1);
                float ix2 = fminf(px2, tx2), iy2 = fminf(py2, ty2);
                float inter = fmaxf(ix2 - ix1, 0.0f) * fmaxf(iy2 - iy1, 0.0f);
                float a1 = (px2 - px1) * (py2 - py1);
                float a2 = (tx2 - tx1) * (ty2 - ty1);
                float uni = a1 + a2 - inter + EPSF;
                float iou = inter / uni;
                float ex1 = fminf(px1, tx1), ey1 = fminf(py1, ty1);
                float ex2 = fmaxf(px2, tx2), ey2 = fmaxf(py2, ty2);
                float cw = ex2 - ex1, chh = ey2 - ey1;
                float c2 = cw * cw + chh * chh + EPSF;
                float dx = px1 + px2 - tx1 - tx2;
                float dy = py1 + py2 - ty1 - ty2;
                float rho2 = (dx * dx + dy * dy) * 0.25f;
                float w1 = px2 - px1, h1 = py2 - py1;
                float w2 = tx2 - tx1, h2 = ty2 - ty1;
                float dat = atanf(w2 / (h2 + EPSF)) - atanf(w1 / (h1 + EPSF));
                float v = 0.40528473f * dat * dat;   // 4/pi^2
                float alpha = v / (1.0f - iou + v + EPSF);
                float ciou = iou - rho2 / c2 - alpha * v;

                if (lane == 0) {
                    lbox = 1.0f - ciou;
                    cnt = 1.0f;
                    float vobj = fmaxf(ciou, 0.0f);
                    unsigned int oldb = atomicMax((unsigned int*)&tobj[cell],
                                                  __float_as_uint(vobj));
                    float old = __uint_as_float(oldb);
                    float nw = fmaxf(vobj, old);
                    corr = wl * pm[4] * (nw - old);
                }

                float xc = pm[5 + lane];
                clsacc = bcef(xc, (lane == cls) ? 1.0f : 0.0f);
                if (lane < 16) {
                    float xc2 = pm[69 + lane];
                    clsacc += bcef(xc2, ((64 + lane) == cls) ? 1.0f : 0.0f);
                }
            }
        }
    }

    __shared__ float s[NT];
    float rb = block_reduce<NT>(lbox, s);
    float rc = block_reduce<NT>(cnt, s);
    float rl = block_reduce<NT>(clsacc, s);
    float rr = block_reduce<NT>(corr, s);
    float ro = block_reduce<NT>(objacc, s);
    if (threadIdx.x == 0) {
        float* p = blockpart + (size_t)blockIdx.x * 5;
        p[0] = rb; p[1] = rc; p[2] = rl; p[3] = rr; p[4] = ro;
    }
}

// ---------------------------------------------------------------------------
// K3: final deterministic combine. Layer partials are stored per-layer
// contiguous in the entry-block region.
// ---------------------------------------------------------------------------
__global__ void final_kernel(const float* __restrict__ blockpart,
                             int sweepBlocks, int bpl2,
                             float* __restrict__ out, int B)
{
    __shared__ float s[NTF];
    int tid = threadIdx.x;
    int total = sweepBlocks + 3 * bpl2;

    float v = 0.0f;   // obj stream term (all blocks; entry blocks have 0)
    for (int i = tid; i < total; i += NTF) v += blockpart[(size_t)i * 5 + 4];
    float objsum = block_reduce<NTF>(v, s);

    v = 0.0f;         // telescoped correction (entry blocks only, others 0)
    for (int i = tid; i < total; i += NTF) v += blockpart[(size_t)i * 5 + 3];
    float corrsum = block_reduce<NTF>(v, s);

    float r_lb[3], r_cnt[3], r_cls[3];
    for (int L = 0; L < 3; ++L) {
        const float* base = blockpart + (size_t)(sweepBlocks + L * bpl2) * 5;
        float v2 = 0.0f;
        for (int i = tid; i < bpl2; i += NTF) v2 += base[(size_t)i * 5 + 0];
        r_lb[L] = block_reduce<NTF>(v2, s);
        v2 = 0.0f;
        for (int i = tid; i < bpl2; i += NTF) v2 += base[(size_t)i * 5 + 1];
        r_cnt[L] = block_reduce<NTF>(v2, s);
        v2 = 0.0f;
        for (int i = tid; i < bpl2; i += NTF) v2 += base[(size_t)i * 5 + 2];
        r_cls[L] = block_reduce<NTF>(v2, s);
    }

    if (tid == 0) {
        float lobj = objsum - corrsum;
        float lb = 0.0f, lc = 0.0f;
        for (int L = 0; L < 3; ++L) {
            if (r_cnt[L] > 0.0f) {
                lb += r_lb[L] / fmaxf(r_cnt[L], 1.0f);
                lc += r_cls[L] / fmaxf(r_cnt[L] * 80.0f, 1.0f);
            }
        }
        out[0] = (0.05f * lb + lobj + 0.5f * lc) * (float)B;
    }
}

extern "C" void kernel_launch(void* const* d_in, const int* in_sizes, int n_in,
                              void* d_out, int out_size, void* d_ws, size_t ws_size,
                              hipStream_t stream) {
    const float* pred0 = (const float*)d_in[0];
    const float* pred1 = (const float*)d_in[1];
    const float* pred2 = (const float*)d_in[2];
    const float* targets = (const float*)d_in[3];

    int B = in_sizes[0] / (3 * 80 * 80 * 85);
    int nt = in_sizes[3] / 6;
    int n0 = B * 3 * 80 * 80;
    int n1 = B * 3 * 40 * 40;
    int n2 = B * 3 * 20 * 20;
    int N = n0 + n1 + n2;
    int perLayer = 15 * nt;
    int sweepBlocks = (N + NT - 1) / NT;          // 394
    int bpl2 = (perLayer + 15) / 16;              // 282 entry blocks / layer
    int grid2 = sweepBlocks + 3 * bpl2;           // 1240 total

    float* tobj = (float*)d_ws;
    float* blockpart = tobj + N;

    int n4 = N / 4;  // 403200 divisible by 4
    zero_kernel<<<(n4 + NT - 1) / NT, NT, 0, stream>>>((float4*)tobj, n4);
    fused_kernel<<<grid2, NT, 0, stream>>>(
        pred0, pred1, pred2, targets, nt, sweepBlocks, bpl2,
        tobj, blockpart, n0, n1, n2);
    final_kernel<<<1, NTF, 0, stream>>>(
        blockpart, sweepBlocks, bpl2, (float*)d_out, B);
}